// Round 5
// baseline (6787.948 us; speedup 1.0000x reference)
//
#include <hip/hip_runtime.h>

typedef _Float16 half8 __attribute__((ext_vector_type(8)));
typedef float f32x4 __attribute__((ext_vector_type(4)));

namespace {
constexpr int kB = 2048;
constexpr int kT = 72;
constexpr int kI = 200;
constexpr int kH = 200;
constexpr int kO = 53;
constexpr int kG = 600;      // 3*kH
constexpr int BT = 16;       // batch rows per WG
constexpr int NWG = kB / BT; // 128
constexpr int MT = 38;       // M tiles of 16 covering 608 (600 padded)
constexpr int KS = 7;        // K slices of 32 covering 224 (200 padded)
constexpr int GSTR = 18;     // LDS G col stride: writes exactly 2-way (free)

// ws layout (float offsets)
constexpr int XW1    = 0;          // [2048][600] emb@Wih1^T + bih1
constexpr int WIH1T  = 1228800;    // [200][600] Wih1 transposed (prep only)
constexpr int FCINT  = 1348800;    // [200][200] fc_in_W transposed (prep only)
constexpr int F0     = 1388800;    // fp16 A-frags: hh1, ih2, hh2, ih3, hh3
constexpr int FSZ    = 68096;      // f32-equiv per frag matrix (38*7*64*8 halfs)
constexpr int FHEAD  = F0 + 5 * FSZ; // fc_out frags (4 tiles)
constexpr int PERM   = MT * KS * 64; // 17024 lane-rows per matrix

// output offsets (floats)
constexpr int OH1 = kB * kT * kO;  // 7815168
constexpr int OH2 = OH1 + kB * kH;
constexpr int OH3 = OH2 + kB * kH;
}

__device__ __forceinline__ float sig_(float x) { return 1.0f / (1.0f + __expf(-x)); }
__device__ __forceinline__ float tanh_(float x) {
    return 1.0f - 2.0f / (__expf(2.0f * x) + 1.0f);
}

// barrier that drains LDS only — in-flight global (register-dest) loads survive.
// Safe here: all cross-wave communication is through LDS; the surviving VMEM ops
// read `ws` weights, which are never written during gru_main.
__device__ __forceinline__ void barrier_l() {
    asm volatile("s_waitcnt lgkmcnt(0)" ::: "memory");
    __builtin_amdgcn_s_barrier();
}

// fp16 fragment-order shadow write of h element (n, j)
__device__ __forceinline__ void store_fb(_Float16* fb, int n, int j, float v) {
    int ks = j >> 5, r = j & 31;
    fb[((ks << 6) + ((r >> 3) << 4) + n) * 8 + (r & 7)] = (_Float16)v;
}

// ---------------- prep kernels ----------------

__global__ __launch_bounds__(256) void prep_transpose2(
    const float* __restrict__ Wih1, const float* __restrict__ fciW,
    float* __restrict__ ws) {
    int idx = blockIdx.x * 256 + threadIdx.x;
    if (idx < 120000) {
        int k = idx / kG, c = idx - k * kG;
        ws[WIH1T + idx] = Wih1[c * kI + k];
    } else {
        int i = idx - 120000;
        if (i < 40000) {
            int k = i / kH, h = i - k * kH;
            ws[FCINT + i] = fciW[h * kI + k];
        }
    }
}

// pack fp16 MFMA A-fragments: frag[mt][ks][lane][8], elem j -> W[mt*16+(lane&15)][ks*32+(lane>>4)*8+j]
__global__ __launch_bounds__(256) void prep_frags(
    const float* __restrict__ Whh1, const float* __restrict__ Wih2,
    const float* __restrict__ Whh2, const float* __restrict__ Wih3,
    const float* __restrict__ Whh3, const float* __restrict__ fcoW,
    float* __restrict__ ws) {
    int idx = blockIdx.x * 256 + threadIdx.x;
    const float* src; int R; long long dstHalf; int rem;
    if (idx < 5 * PERM) {
        int m = idx / PERM; rem = idx - m * PERM;
        switch (m) {
            case 0: src = Whh1; break;
            case 1: src = Wih2; break;
            case 2: src = Whh2; break;
            case 3: src = Wih3; break;
            default: src = Whh3; break;
        }
        R = kG; dstHalf = 2LL * (F0 + m * FSZ);
    } else {
        rem = idx - 5 * PERM;
        if (rem >= 4 * KS * 64) return;
        src = fcoW; R = kO; dstHalf = 2LL * FHEAD;
    }
    int lane = rem & 63;
    int tmp = rem >> 6;
    int ks = tmp % KS;
    int mt = tmp / KS;
    int row = mt * 16 + (lane & 15);
    int k0 = ks * 32 + (lane >> 4) * 8;
    half8 v;
    #pragma unroll
    for (int j = 0; j < 8; ++j) {
        int k = k0 + j;
        v[j] = (_Float16)((row < R && k < kH) ? src[row * kH + k] : 0.0f);
    }
    *(half8*)((_Float16*)ws + dstHalf + (long long)rem * 8) = v;
}

// One block per batch row: BN -> fc_in+ReLU -> xw1 = emb@Wih1^T + bih1
__global__ __launch_bounds__(256) void prep_input(
    const float* __restrict__ enc,
    const float* __restrict__ bn_g, const float* __restrict__ bn_b,
    const float* __restrict__ bn_m, const float* __restrict__ bn_v,
    const float* __restrict__ fcib, const float* __restrict__ bih1,
    float* ws) {
    __shared__ float xh[kI];
    __shared__ float emb[kH];
    const int b = blockIdx.x, tid = threadIdx.x;
    const float* fcInT = ws + FCINT;
    const float* Wih1T = ws + WIH1T;
    if (tid < kI) {
        float x = enc[b * kI + tid];
        xh[tid] = (x - bn_m[tid]) * rsqrtf(bn_v[tid] + 1e-5f) * bn_g[tid] + bn_b[tid];
    }
    __syncthreads();
    if (tid < kH) {
        float s = fcib[tid];
        for (int k = 0; k < kI; ++k) s = fmaf(xh[k], fcInT[k * kH + tid], s);
        emb[tid] = fmaxf(s, 0.0f);
    }
    __syncthreads();
    for (int c = tid; c < kG; c += 256) {
        float s = bih1[c];
        for (int k = 0; k < kH; ++k) s = fmaf(emb[k], Wih1T[k * kG + c], s);
        ws[XW1 + b * kG + c] = s;
    }
}

// weight-tile load: 6 full slices + predicated ks=6 pad slice (real k only on lanes 0-15)
#define LDW(dst, WB, mt) do { \
    const half8* _p = (WB) + ((mt) * KS) * 64 + ln; \
    _Pragma("unroll") \
    for (int _k = 0; _k < KS - 1; ++_k) (dst)[_k] = _p[_k * 64]; \
    if (lo) (dst)[KS - 1] = _p[(KS - 1) * 64]; else (dst)[KS - 1] = z8; \
  } while (0)

#define MM1(wrg, mt) do { \
    f32x4 _acc = {0.f, 0.f, 0.f, 0.f}; \
    _Pragma("unroll") \
    for (int _k = 0; _k < KS; ++_k) \
      _acc = __builtin_amdgcn_mfma_f32_16x16x32_f16((wrg)[_k], bf[_k], _acc, 0, 0, 0); \
    const int _row = (mt) * 16 + lb * 4; \
    _Pragma("unroll") \
    for (int _r = 0; _r < 4; ++_r) Gs[(_row + _r) * GSTR + lr] = _acc[_r]; \
  } while (0)

#define MM2(wx, wh, mt) do { \
    f32x4 _ax = {0.f, 0.f, 0.f, 0.f}, _ah = {0.f, 0.f, 0.f, 0.f}; \
    _Pragma("unroll") \
    for (int _k = 0; _k < KS; ++_k) { \
      _ax = __builtin_amdgcn_mfma_f32_16x16x32_f16((wx)[_k], bfx[_k], _ax, 0, 0, 0); \
      _ah = __builtin_amdgcn_mfma_f32_16x16x32_f16((wh)[_k], bfh[_k], _ah, 0, 0, 0); \
    } \
    const int _row = (mt) * 16 + lb * 4; \
    if ((mt) < 25) { \
      _Pragma("unroll") \
      for (int _r = 0; _r < 4; ++_r) Gs[(_row + _r) * GSTR + lr] = _ax[_r] + _ah[_r]; \
    } else { \
      _Pragma("unroll") \
      for (int _r = 0; _r < 4; ++_r) { \
        Gs[(_row + _r) * GSTR + lr] = _ax[_r]; \
        Gns[(_row - 400 + _r) * GSTR + lr] = _ah[_r]; \
      } \
    } \
  } while (0)

// ---------------- main persistent GRU kernel ----------------
// 128 WGs x 1024 threads (16 waves). WG owns 16 batch rows. MFMA 16x16x32 f16.
// Weight stream is register-prefetched 1-2 phases ahead; barriers drain LDS only,
// so VMEM runs continuously across the whole step instead of per-phase bursts.
__global__ __launch_bounds__(1024, 4) void gru_main(
    const float* __restrict__ ws,
    const float* __restrict__ h1in, const float* __restrict__ h2in,
    const float* __restrict__ h3in,
    const float* __restrict__ bhh1,
    const float* __restrict__ bih2, const float* __restrict__ bhh2,
    const float* __restrict__ bih3, const float* __restrict__ bhh3,
    const float* __restrict__ fcob,
    float* __restrict__ out) {
    __shared__ float xwL[kG * BT];                         // 38400 B, [j][n]
    __shared__ __align__(16) _Float16 fb1[KS * 64 * 8];    // 7168 B each
    __shared__ __align__(16) _Float16 fb2[KS * 64 * 8];
    __shared__ __align__(16) _Float16 fb3[KS * 64 * 8];
    __shared__ float Gs[608 * GSTR];                       // 43776 B
    __shared__ float Gns[208 * GSTR];                      // 14976 B
    __shared__ float bias[9 * kH];                         // 7200 B
    __shared__ float hb[64];

    const int tid = threadIdx.x, wv = tid >> 6, ln = tid & 63;
    const int lb = ln >> 4, lr = ln & 15;
    const int b0 = blockIdx.x * BT;
    const int mt0 = wv, mt1 = wv + 16, mt2 = wv + 32;
    const bool has3 = (mt2 < MT);
    const bool lo = (ln < 16);
    half8 z8;
    #pragma unroll
    for (int j = 0; j < 8; ++j) z8[j] = (_Float16)0.0f;

    // ---- stage xw1 (time-invariant) into LDS, folding bhh1 r/z biases
    for (int i = tid; i < kG * BT; i += 1024) {
        int n = i / kG, j = i - n * kG;
        float v = ws[XW1 + (b0 + n) * kG + j];
        if (j < 2 * kH) v += bhh1[j];
        xwL[j * BT + n] = v;
    }
    // ---- biases: [0]=b1n [1]=b2r [2]=b2z [3]=b2xn [4]=b2hn [5..8]=L3
    for (int i = tid; i < 9 * kH; i += 1024) {
        int c = i / kH, j = i - c * kH;
        float v;
        switch (c) {
            case 0:  v = bhh1[2 * kH + j]; break;
            case 1:  v = bih2[j] + bhh2[j]; break;
            case 2:  v = bih2[kH + j] + bhh2[kH + j]; break;
            case 3:  v = bih2[2 * kH + j]; break;
            case 4:  v = bhh2[2 * kH + j]; break;
            case 5:  v = bih3[j] + bhh3[j]; break;
            case 6:  v = bih3[kH + j] + bhh3[kH + j]; break;
            case 7:  v = bih3[2 * kH + j]; break;
            default: v = bhh3[2 * kH + j]; break;
        }
        bias[i] = v;
    }
    if (tid < 64) hb[tid] = (tid < kO) ? fcob[tid] : 0.0f;

    // ---- h states -> registers + fp16 frag shadows
    float h1r[4], h2r[4], h3r[4];
    #pragma unroll
    for (int s = 0; s < 4; ++s) {
        int idx = tid + s * 1024;
        if (idx < BT * kH) {
            int n = idx & 15, j = idx >> 4;
            h1r[s] = h1in[(b0 + n) * kH + j];
            h2r[s] = h2in[(b0 + n) * kH + j];
            h3r[s] = h3in[(b0 + n) * kH + j];
            store_fb(fb1, n, j, h1r[s]);
            store_fb(fb2, n, j, h2r[s]);
            store_fb(fb3, n, j, h3r[s]);
        } else { h1r[s] = h2r[s] = h3r[s] = 0.0f; }
    }
    // zero fp16 K-pad (ks=6, k=200..223 -> frag slots lane 16..63)
    for (int i = tid; i < 3 * 48 * 8; i += 1024) {
        int w = i / 384, r = i - w * 384;
        int lane = 16 + (r >> 3), jj = r & 7;
        _Float16* f = (w == 0) ? fb1 : (w == 1) ? fb2 : fb3;
        f[(6 * 64 + lane) * 8 + jj] = (_Float16)0.0f;
    }
    __syncthreads();

    const half8* WFhh1 = (const half8*)(ws + F0);
    const half8* WFih2 = (const half8*)(ws + F0 + FSZ);
    const half8* WFhh2 = (const half8*)(ws + F0 + 2 * FSZ);
    const half8* WFih3 = (const half8*)(ws + F0 + 3 * FSZ);
    const half8* WFhh3 = (const half8*)(ws + F0 + 4 * FSZ);
    const half8* WFhead = (const half8*)(ws + FHEAD);

    // ---- prefetch registers
    half8 w1a[KS], w1b[KS], w1c[KS];
    half8 w2xa[KS], w2xb[KS], w2xc[KS], w2ha[KS], w2hb[KS], w2hc[KS];
    half8 w3xa[KS], w3xb[KS], w3xc[KS], w3ha[KS], w3hb[KS], w3hc[KS];
    half8 whd[KS];

    // prologue: L1 weights for t=0; head weights (constant over t)
    LDW(w1a, WFhh1, mt0); LDW(w1b, WFhh1, mt1); if (has3) LDW(w1c, WFhh1, mt2);
    if (wv < 4) LDW(whd, WFhead, wv);

    for (int t = 0; t < kT; ++t) {
        // ---------- M1: Gs = Whh1 x h1; issue ih2 prefetch ----------
        {
            LDW(w2xa, WFih2, mt0); LDW(w2xb, WFih2, mt1); if (has3) LDW(w2xc, WFih2, mt2);
            half8 bf[KS];
            #pragma unroll
            for (int ks = 0; ks < KS; ++ks)
                bf[ks] = *(const half8*)(fb1 + (ks * 64 + ln) * 8);
            MM1(w1a, mt0); MM1(w1b, mt1); if (has3) MM1(w1c, mt2);
        }
        barrier_l();
        // ---------- U1: update h1; issue hh2 prefetch ----------
        LDW(w2ha, WFhh2, mt0); LDW(w2hb, WFhh2, mt1); if (has3) LDW(w2hc, WFhh2, mt2);
        #pragma unroll
        for (int s = 0; s < 4; ++s) {
            int idx = tid + s * 1024;
            if (idx < BT * kH) {
                int n = idx & 15, j = idx >> 4;
                float r  = sig_(xwL[j * BT + n]            + Gs[j * GSTR + n]);
                float z  = sig_(xwL[(kH + j) * BT + n]     + Gs[(kH + j) * GSTR + n]);
                float nn = tanh_(xwL[(2 * kH + j) * BT + n] + r * (Gs[(2 * kH + j) * GSTR + n] + bias[j]));
                h1r[s] = (1.0f - z) * nn + z * h1r[s];
                store_fb(fb1, n, j, h1r[s]);
            }
        }
        barrier_l();
        // ---------- M2: Gs/Gns = Wih2 x h1 + Whh2 x h2; issue ih3 prefetch ----------
        {
            LDW(w3xa, WFih3, mt0); LDW(w3xb, WFih3, mt1); if (has3) LDW(w3xc, WFih3, mt2);
            half8 bfx[KS], bfh[KS];
            #pragma unroll
            for (int ks = 0; ks < KS; ++ks) {
                bfx[ks] = *(const half8*)(fb1 + (ks * 64 + ln) * 8);
                bfh[ks] = *(const half8*)(fb2 + (ks * 64 + ln) * 8);
            }
            MM2(w2xa, w2ha, mt0); MM2(w2xb, w2hb, mt1); if (has3) MM2(w2xc, w2hc, mt2);
        }
        barrier_l();
        // ---------- U2: update h2; issue hh3 prefetch ----------
        LDW(w3ha, WFhh3, mt0); LDW(w3hb, WFhh3, mt1); if (has3) LDW(w3hc, WFhh3, mt2);
        #pragma unroll
        for (int s = 0; s < 4; ++s) {
            int idx = tid + s * 1024;
            if (idx < BT * kH) {
                int n = idx & 15, j = idx >> 4;
                float r  = sig_(Gs[j * GSTR + n]            + bias[kH + j]);
                float z  = sig_(Gs[(kH + j) * GSTR + n]     + bias[2 * kH + j]);
                float nn = tanh_(Gs[(2 * kH + j) * GSTR + n] + bias[3 * kH + j]
                                 + r * (Gns[j * GSTR + n]   + bias[4 * kH + j]));
                h2r[s] = (1.0f - z) * nn + z * h2r[s];
                store_fb(fb2, n, j, h2r[s]);
            }
        }
        barrier_l();
        // ---------- M3: Gs/Gns = Wih3 x h2 + Whh3 x h3; issue next-step hh1 prefetch ----------
        {
            LDW(w1a, WFhh1, mt0); LDW(w1b, WFhh1, mt1); if (has3) LDW(w1c, WFhh1, mt2);
            half8 bfx[KS], bfh[KS];
            #pragma unroll
            for (int ks = 0; ks < KS; ++ks) {
                bfx[ks] = *(const half8*)(fb2 + (ks * 64 + ln) * 8);
                bfh[ks] = *(const half8*)(fb3 + (ks * 64 + ln) * 8);
            }
            MM2(w3xa, w3ha, mt0); MM2(w3xb, w3hb, mt1); if (has3) MM2(w3xc, w3hc, mt2);
        }
        barrier_l();
        // ---------- U3: update h3 ----------
        #pragma unroll
        for (int s = 0; s < 4; ++s) {
            int idx = tid + s * 1024;
            if (idx < BT * kH) {
                int n = idx & 15, j = idx >> 4;
                float r  = sig_(Gs[j * GSTR + n]            + bias[5 * kH + j]);
                float z  = sig_(Gs[(kH + j) * GSTR + n]     + bias[6 * kH + j]);
                float nn = tanh_(Gs[(2 * kH + j) * GSTR + n] + bias[7 * kH + j]
                                 + r * (Gns[j * GSTR + n]   + bias[8 * kH + j]));
                h3r[s] = (1.0f - z) * nn + z * h3r[s];
                store_fb(fb3, n, j, h3r[s]);
            }
        }
        barrier_l();
        // ---------- HEAD (waves 0..3): sigmoid(h3 @ fc_out^T + b) ----------
        if (wv < 4) {
            half8 bf[KS];
            #pragma unroll
            for (int ks = 0; ks < KS; ++ks)
                bf[ks] = *(const half8*)(fb3 + (ks * 64 + ln) * 8);
            f32x4 acc = {0.f, 0.f, 0.f, 0.f};
            #pragma unroll
            for (int ks = 0; ks < KS; ++ks)
                acc = __builtin_amdgcn_mfma_f32_16x16x32_f16(whd[ks], bf[ks], acc, 0, 0, 0);
            int o0 = wv * 16 + lb * 4;
            int obase = (b0 + lr) * (kT * kO) + t * kO;
            #pragma unroll
            for (int rg = 0; rg < 4; ++rg) {
                int o = o0 + rg;
                if (o < kO) out[obase + o] = sig_(acc[rg] + hb[o]);
            }
        }
        barrier_l();
    }

    // ---- final hidden states: stage in LDS (Gs) for coalesced global writes
    #pragma unroll
    for (int s = 0; s < 4; ++s) {
        int idx = tid + s * 1024;
        if (idx < BT * kH) {
            Gs[idx] = h1r[s];
            Gs[3200 + idx] = h2r[s];
            Gs[6400 + idx] = h3r[s];
        }
    }
    __syncthreads();
    for (int i = tid; i < BT * kH; i += 1024) {
        int n = i / kH, j = i - n * kH;
        int src = j * BT + n;
        out[OH1 + (b0 + n) * kH + j] = Gs[src];
        out[OH2 + (b0 + n) * kH + j] = Gs[3200 + src];
        out[OH3 + (b0 + n) * kH + j] = Gs[6400 + src];
    }
}

extern "C" void kernel_launch(void* const* d_in, const int* in_sizes, int n_in,
                              void* d_out, int out_size, void* d_ws, size_t ws_size,
                              hipStream_t stream) {
    (void)in_sizes; (void)n_in; (void)out_size; (void)ws_size;
    const float* enc  = (const float*)d_in[0];
    const float* h1in = (const float*)d_in[1];
    const float* h2in = (const float*)d_in[2];
    const float* h3in = (const float*)d_in[3];
    const float* bn_g = (const float*)d_in[4];
    const float* bn_b = (const float*)d_in[5];
    const float* bn_m = (const float*)d_in[6];
    const float* bn_v = (const float*)d_in[7];
    const float* fciW = (const float*)d_in[8];
    const float* fcib = (const float*)d_in[9];
    const float* Wih1 = (const float*)d_in[10];
    const float* Whh1 = (const float*)d_in[11];
    const float* bih1 = (const float*)d_in[12];
    const float* bhh1 = (const float*)d_in[13];
    const float* Wih2 = (const float*)d_in[14];
    const float* Whh2 = (const float*)d_in[15];
    const float* bih2 = (const float*)d_in[16];
    const float* bhh2 = (const float*)d_in[17];
    const float* Wih3 = (const float*)d_in[18];
    const float* Whh3 = (const float*)d_in[19];
    const float* bih3 = (const float*)d_in[20];
    const float* bhh3 = (const float*)d_in[21];
    const float* fcoW = (const float*)d_in[22];
    const float* fcob = (const float*)d_in[23];
    float* ws  = (float*)d_ws;
    float* out = (float*)d_out;

    hipLaunchKernelGGL(prep_transpose2, dim3(625), dim3(256), 0, stream, Wih1, fciW, ws);
    hipLaunchKernelGGL(prep_frags, dim3(340), dim3(256), 0, stream,
                       Whh1, Wih2, Whh2, Wih3, Whh3, fcoW, ws);
    hipLaunchKernelGGL(prep_input, dim3(kB), dim3(256), 0, stream,
                       enc, bn_g, bn_b, bn_m, bn_v, fcib, bih1, ws);
    hipLaunchKernelGGL(gru_main, dim3(NWG), dim3(1024), 0, stream,
                       ws, h1in, h2in, h3in, bhh1, bih2, bhh2, bih3, bhh3, fcob, out);
}

// Round 6
// 2318.569 us; speedup vs baseline: 2.9276x; 2.9276x over previous
//
#include <hip/hip_runtime.h>

typedef _Float16 half8 __attribute__((ext_vector_type(8)));
typedef _Float16 half4_ __attribute__((ext_vector_type(4)));
typedef float f32x4 __attribute__((ext_vector_type(4)));

namespace {
constexpr int kB = 2048;
constexpr int kT = 72;
constexpr int kI = 200;
constexpr int kH = 200;
constexpr int kO = 53;
constexpr int kG = 600;      // 3*kH
constexpr int BT = 16;       // batch rows per WG
constexpr int NWG = kB / BT; // 128
constexpr int KS = 7;        // K slices of 32 covering 224 (200 padded)
constexpr int MT2 = 39;      // 13 jblocks x 3 gates (r,z,n interleaved tiles)
constexpr int PERM2 = MT2 * KS * 64; // 17472 lane-rows per matrix

// ws layout (float offsets). Order of kernels: transpose2 -> input -> frags -> main.
// frags overwrite the prep-only WIH1T/FCINT region (read only by prep_input).
constexpr int XW1    = 0;          // [2048][600] emb@Wih1^T + bih1
constexpr int WIH1T  = 1228800;    // [200][600] Wih1^T (prep_input only)
constexpr int FCINT  = 1348800;    // [200][200] fc_in_W^T (prep_input only)
constexpr int F0     = 1228800;    // fp16 A-frags: hh1, ih2, hh2, ih3, hh3 (after prep_input)
constexpr int FSZ2   = 69888;      // floats per frag matrix (39*7*64*8 halves / 2)
constexpr int FHEAD  = F0 + 5 * FSZ2; // 1578240; head frags (4 tiles)

// output offsets (floats)
constexpr int OH1 = kB * kT * kO;  // 7815168
constexpr int OH2 = OH1 + kB * kH;
constexpr int OH3 = OH2 + kB * kH;
}

__device__ __forceinline__ float sig_(float x) { return 1.0f / (1.0f + __expf(-x)); }
__device__ __forceinline__ float tanh_(float x) {
    return 1.0f - 2.0f / (__expf(2.0f * x) + 1.0f);
}

// barrier draining LDS only; in-flight global weight loads (vmcnt) survive.
// Single asm block so no memory op can slip between waitcnt and s_barrier.
__device__ __forceinline__ void barx() {
    asm volatile("s_waitcnt lgkmcnt(0)\n\ts_barrier" ::: "memory");
}

// ---------------- prep kernels ----------------

__global__ __launch_bounds__(256) void prep_transpose2(
    const float* __restrict__ Wih1, const float* __restrict__ fciW,
    float* __restrict__ ws) {
    int idx = blockIdx.x * 256 + threadIdx.x;
    if (idx < 120000) {
        int k = idx / kG, c = idx - k * kG;
        ws[WIH1T + idx] = Wih1[c * kI + k];
    } else {
        int i = idx - 120000;
        if (i < 40000) {
            int k = i / kH, h = i - k * kH;
            ws[FCINT + i] = fciW[h * kI + k];
        }
    }
}

// One block per batch row: BN -> fc_in+ReLU -> xw1 = emb@Wih1^T + bih1
__global__ __launch_bounds__(256) void prep_input(
    const float* __restrict__ enc,
    const float* __restrict__ bn_g, const float* __restrict__ bn_b,
    const float* __restrict__ bn_m, const float* __restrict__ bn_v,
    const float* __restrict__ fcib, const float* __restrict__ bih1,
    float* ws) {
    __shared__ float xh[kI];
    __shared__ float emb[kH];
    const int b = blockIdx.x, tid = threadIdx.x;
    const float* fcInT = ws + FCINT;
    const float* Wih1T = ws + WIH1T;
    if (tid < kI) {
        float x = enc[b * kI + tid];
        xh[tid] = (x - bn_m[tid]) * rsqrtf(bn_v[tid] + 1e-5f) * bn_g[tid] + bn_b[tid];
    }
    __syncthreads();
    if (tid < kH) {
        float s = fcib[tid];
        for (int k = 0; k < kI; ++k) s = fmaf(xh[k], fcInT[k * kH + tid], s);
        emb[tid] = fmaxf(s, 0.0f);
    }
    __syncthreads();
    for (int c = tid; c < kG; c += 256) {
        float s = bih1[c];
        for (int k = 0; k < kH; ++k) s = fmaf(emb[k], Wih1T[k * kG + c], s);
        ws[XW1 + b * kG + c] = s;
    }
}

// pack fp16 MFMA A-fragments, gate-triplet tile order:
// tile mt = 3*b + g  (b = jblock 0..12, g = gate r/z/n)
// frag elem j of lane: W[g*200 + b*16 + (lane&15)][ks*32 + (lane>>4)*8 + j]
__global__ __launch_bounds__(256) void prep_frags(
    const float* __restrict__ Whh1, const float* __restrict__ Wih2,
    const float* __restrict__ Whh2, const float* __restrict__ Wih3,
    const float* __restrict__ Whh3, const float* __restrict__ fcoW,
    float* __restrict__ ws) {
    int idx = blockIdx.x * 256 + threadIdx.x;
    if (idx < 5 * PERM2) {
        int m = idx / PERM2, rem = idx - m * PERM2;
        const float* src;
        switch (m) {
            case 0: src = Whh1; break;
            case 1: src = Wih2; break;
            case 2: src = Whh2; break;
            case 3: src = Wih3; break;
            default: src = Whh3; break;
        }
        int lane = rem & 63;
        int tmp = rem >> 6;
        int ks = tmp % KS;
        int mt = tmp / KS;
        int b = mt / 3, g = mt - 3 * b;
        int rt = b * 16 + (lane & 15);       // j index within layer (0..207)
        int row = g * kH + rt;               // original matrix row
        int k0 = ks * 32 + (lane >> 4) * 8;
        half8 v;
        #pragma unroll
        for (int j = 0; j < 8; ++j) {
            int k = k0 + j;
            v[j] = (_Float16)((rt < kH && k < kH) ? src[row * kH + k] : 0.0f);
        }
        *(half8*)((_Float16*)ws + 2LL * (F0 + m * FSZ2) + (long long)rem * 8) = v;
    } else {
        int rem = idx - 5 * PERM2;
        if (rem >= 4 * KS * 64) return;
        int lane = rem & 63;
        int tmp = rem >> 6;
        int ks = tmp % KS;
        int mt = tmp / KS;
        int row = mt * 16 + (lane & 15);
        int k0 = ks * 32 + (lane >> 4) * 8;
        half8 v;
        #pragma unroll
        for (int j = 0; j < 8; ++j) {
            int k = k0 + j;
            v[j] = (_Float16)((row < kO && k < kH) ? fcoW[row * kH + k] : 0.0f);
        }
        *(half8*)((_Float16*)ws + 2LL * FHEAD + (long long)rem * 8) = v;
    }
}

// fused layer-2/3 phase: two matmuls (x-proj + h-proj) + in-register GRU update
__device__ __forceinline__ void layer23(
    const half8* __restrict__ px, const half8* __restrict__ ph,
    const _Float16* __restrict__ fx, const _Float16* __restrict__ fh,
    const float* __restrict__ bsb,       // 4 consecutive [208] arrays: r, z, xn, hn
    float* hreg, _Float16* __restrict__ fbdst, int fboff,
    int j0, int ln) {
    f32x4 ar = {0,0,0,0}, az = {0,0,0,0}, anx = {0,0,0,0}, anh = {0,0,0,0};
    half8 xr = px[0], xz = px[KS * 64], xn = px[2 * KS * 64];
    half8 hr = ph[0], hz = ph[KS * 64], hn = ph[2 * KS * 64];
    #pragma unroll
    for (int ks = 0; ks < KS; ++ks) {
        half8 xr2, xz2, xn2, hr2, hz2, hn2;
        if (ks < KS - 1) {
            xr2 = px[(ks + 1) * 64]; xz2 = px[KS * 64 + (ks + 1) * 64]; xn2 = px[2 * KS * 64 + (ks + 1) * 64];
            hr2 = ph[(ks + 1) * 64]; hz2 = ph[KS * 64 + (ks + 1) * 64]; hn2 = ph[2 * KS * 64 + (ks + 1) * 64];
        }
        half8 bx = *(const half8*)(fx + ((ks * 64 + ln) << 3));
        half8 bh = *(const half8*)(fh + ((ks * 64 + ln) << 3));
        ar  = __builtin_amdgcn_mfma_f32_16x16x32_f16(xr, bx, ar, 0, 0, 0);
        ar  = __builtin_amdgcn_mfma_f32_16x16x32_f16(hr, bh, ar, 0, 0, 0);
        az  = __builtin_amdgcn_mfma_f32_16x16x32_f16(xz, bx, az, 0, 0, 0);
        az  = __builtin_amdgcn_mfma_f32_16x16x32_f16(hz, bh, az, 0, 0, 0);
        anx = __builtin_amdgcn_mfma_f32_16x16x32_f16(xn, bx, anx, 0, 0, 0);
        anh = __builtin_amdgcn_mfma_f32_16x16x32_f16(hn, bh, anh, 0, 0, 0);
        if (ks < KS - 1) { xr = xr2; xz = xz2; xn = xn2; hr = hr2; hz = hz2; hn = hn2; }
    }
    half4_ hv;
    #pragma unroll
    for (int rg = 0; rg < 4; ++rg) {
        int j = j0 + rg;
        float r  = sig_(ar[rg] + bsb[j]);
        float z  = sig_(az[rg] + bsb[208 + j]);
        float nn = tanh_(anx[rg] + bsb[2 * 208 + j] + r * (anh[rg] + bsb[3 * 208 + j]));
        hreg[rg] = (1.0f - z) * nn + z * hreg[rg];
        hv[rg] = (_Float16)hreg[rg];
    }
    *(half4_*)(&fbdst[fboff]) = hv;
}

// head: sigmoid(h3 @ fc_out^T + b) for timestep tt, reading fb3 slice fr
__device__ __forceinline__ void head_mm(
    const half8* __restrict__ WFhd, const _Float16* __restrict__ fr,
    const float* __restrict__ hb, float* __restrict__ out,
    int hw, int tt, int b0, int ln, int lq, int lr) {
    const half8* pw0 = WFhd + hw * (KS * 64) + ln;
    const half8* pw1 = WFhd + 3 * (KS * 64) + ln;   // tile 3, done by hw==0
    f32x4 a0 = {0,0,0,0}, a1 = {0,0,0,0};
    #pragma unroll
    for (int ks = 0; ks < KS; ++ks) {
        half8 bfv = *(const half8*)(fr + ((ks * 64 + ln) << 3));
        a0 = __builtin_amdgcn_mfma_f32_16x16x32_f16(pw0[ks * 64], bfv, a0, 0, 0, 0);
        if (hw == 0) a1 = __builtin_amdgcn_mfma_f32_16x16x32_f16(pw1[ks * 64], bfv, a1, 0, 0, 0);
    }
    int obase = (b0 + lr) * (kT * kO) + tt * kO;
    #pragma unroll
    for (int rg = 0; rg < 4; ++rg) {
        int o = hw * 16 + lq * 4 + rg;
        if (o < kO) out[obase + o] = sig_(a0[rg] + hb[o]);
    }
    if (hw == 0) {
        #pragma unroll
        for (int rg = 0; rg < 4; ++rg) {
            int o = 48 + lq * 4 + rg;
            if (o < kO) out[obase + o] = sig_(a1[rg] + hb[o]);
        }
    }
}

// ---------------- main persistent GRU kernel ----------------
// 128 WGs x 1024 threads (16 waves). Waves 0..12 each own one 16-row jblock:
// compute r/z/n gate tiles via MFMA and apply the GRU update in-register
// (C-fragment lane == (j,n) owner). h masters live in registers. fb (fp16
// MFMA-B-order h shadows) are ping-pong buffered; 3 lgkm-only barriers/step.
// Waves 13..15 compute the output head for step t-1 during phase L1.
__global__ __launch_bounds__(1024, 4) void gru_main(
    const float* __restrict__ ws,
    const float* __restrict__ h1in, const float* __restrict__ h2in,
    const float* __restrict__ h3in,
    const float* __restrict__ bhh1,
    const float* __restrict__ bih2, const float* __restrict__ bhh2,
    const float* __restrict__ bih3, const float* __restrict__ bhh3,
    const float* __restrict__ fcob,
    float* __restrict__ out) {
    __shared__ float xw1f[3][208 * 17];                 // 42432 B  (xw1 + folded biases), stride 17
    __shared__ float bs[9][208];                        // 7488 B
    __shared__ __align__(16) _Float16 fb[3][2][KS * 64 * 8];  // 43008 B (ping-pong h shadows)
    __shared__ float hb[64];

    const int tid = threadIdx.x, wv = tid >> 6, ln = tid & 63;
    const int lq = ln >> 4, lr = ln & 15;
    const int b0 = blockIdx.x * BT;
    const bool own = (wv < 13);

    // ---- stage xw1 (+ bih1 already folded; add bhh1 for r,z) into LDS
    for (int i = tid; i < 3 * 208 * 16; i += 1024) {
        int g = i / (208 * 16), rem = i - g * (208 * 16), j = rem >> 4, n = rem & 15;
        float v = 0.0f;
        if (j < kH) {
            v = ws[XW1 + (b0 + n) * kG + g * kH + j];
            if (g < 2) v += bhh1[g * kH + j];
        }
        xw1f[g][j * 17 + n] = v;
    }
    // ---- biases (208-padded): 0=bhh1_n 1=b2r 2=b2z 3=b2xn 4=b2hn 5=b3r 6=b3z 7=b3xn 8=b3hn
    for (int i = tid; i < 9 * 208; i += 1024) {
        int c = i / 208, j = i - c * 208;
        float v = 0.0f;
        if (j < kH) {
            switch (c) {
                case 0: v = bhh1[2 * kH + j]; break;
                case 1: v = bih2[j] + bhh2[j]; break;
                case 2: v = bih2[kH + j] + bhh2[kH + j]; break;
                case 3: v = bih2[2 * kH + j]; break;
                case 4: v = bhh2[2 * kH + j]; break;
                case 5: v = bih3[j] + bhh3[j]; break;
                case 6: v = bih3[kH + j] + bhh3[kH + j]; break;
                case 7: v = bih3[2 * kH + j]; break;
                default: v = bhh3[2 * kH + j]; break;
            }
        }
        bs[c][j] = v;
    }
    if (tid < 64) hb[tid] = (tid < kO) ? fcob[tid] : 0.0f;

    // ---- zero never-written fb tail (ks=6, lanes 32..63 = j 208..223), both parities
    for (int i = tid; i < 3 * 2 * 32 * 8; i += 1024) {
        int l3 = i / 512, rem = i - l3 * 512, par = rem >> 8, r2 = rem & 255;
        fb[l3][par][(6 * 64 + 32 + (r2 >> 3)) * 8 + (r2 & 7)] = (_Float16)0.0f;
    }

    // ---- h states -> registers; parity-0 fb shadows
    float h1r[4], h2r[4], h3r[4];
    const int j0 = wv * 16 + lq * 4;
    int fboff = 0;
    if (own) {
        int ks6 = j0 >> 5, rr = j0 & 31;
        fboff = (((ks6 << 6) + ((rr >> 3) << 4) + lr) << 3) + (rr & 7);
        half4_ v1, v2, v3;
        #pragma unroll
        for (int rg = 0; rg < 4; ++rg) {
            int j = j0 + rg;
            h1r[rg] = (j < kH) ? h1in[(b0 + lr) * kH + j] : 0.0f;
            h2r[rg] = (j < kH) ? h2in[(b0 + lr) * kH + j] : 0.0f;
            h3r[rg] = (j < kH) ? h3in[(b0 + lr) * kH + j] : 0.0f;
            v1[rg] = (_Float16)h1r[rg];
            v2[rg] = (_Float16)h2r[rg];
            v3[rg] = (_Float16)h3r[rg];
        }
        *(half4_*)(&fb[0][0][fboff]) = v1;
        *(half4_*)(&fb[1][0][fboff]) = v2;
        *(half4_*)(&fb[2][0][fboff]) = v3;
    } else {
        #pragma unroll
        for (int rg = 0; rg < 4; ++rg) { h1r[rg] = h2r[rg] = h3r[rg] = 0.0f; }
    }
    __syncthreads();

    const half8* WF1  = (const half8*)(ws + F0);
    const half8* WF2x = (const half8*)(ws + F0 + 1 * FSZ2);
    const half8* WF2h = (const half8*)(ws + F0 + 2 * FSZ2);
    const half8* WF3x = (const half8*)(ws + F0 + 3 * FSZ2);
    const half8* WF3h = (const half8*)(ws + F0 + 4 * FSZ2);
    const half8* WFhd = (const half8*)(ws + FHEAD);
    const int tb = 3 * wv * (KS * 64);   // this wave's r-tile element offset

    for (int t = 0; t < kT; ++t) {
        const int p = t & 1, q = p ^ 1;
        // ---------- phase L1 (waves 0-12)  ||  head(t-1) (waves 13-15) ----------
        if (own) {
            const half8* pw = WF1 + tb + ln;
            const _Float16* fr = fb[0][p];
            f32x4 ra = {0,0,0,0}, za = {0,0,0,0}, na = {0,0,0,0};
            half8 wr = pw[0], wz = pw[KS * 64], wn = pw[2 * KS * 64];
            #pragma unroll
            for (int ks = 0; ks < KS; ++ks) {
                half8 wr2, wz2, wn2;
                if (ks < KS - 1) {
                    wr2 = pw[(ks + 1) * 64];
                    wz2 = pw[KS * 64 + (ks + 1) * 64];
                    wn2 = pw[2 * KS * 64 + (ks + 1) * 64];
                }
                half8 bfv = *(const half8*)(fr + ((ks * 64 + ln) << 3));
                ra = __builtin_amdgcn_mfma_f32_16x16x32_f16(wr, bfv, ra, 0, 0, 0);
                za = __builtin_amdgcn_mfma_f32_16x16x32_f16(wz, bfv, za, 0, 0, 0);
                na = __builtin_amdgcn_mfma_f32_16x16x32_f16(wn, bfv, na, 0, 0, 0);
                if (ks < KS - 1) { wr = wr2; wz = wz2; wn = wn2; }
            }
            half4_ hv;
            #pragma unroll
            for (int rg = 0; rg < 4; ++rg) {
                int j = j0 + rg;
                float r  = sig_(xw1f[0][j * 17 + lr] + ra[rg]);
                float z  = sig_(xw1f[1][j * 17 + lr] + za[rg]);
                float nn = tanh_(xw1f[2][j * 17 + lr] + r * (na[rg] + bs[0][j]));
                h1r[rg] = (1.0f - z) * nn + z * h1r[rg];
                hv[rg] = (_Float16)h1r[rg];
            }
            *(half4_*)(&fb[0][q][fboff]) = hv;
        } else if (t > 0) {
            head_mm(WFhd, fb[2][p], hb, out, wv - 13, t - 1, b0, ln, lq, lr);
        }
        barx();
        // ---------- phase L2 ----------
        if (own) {
            layer23(WF2x + tb + ln, WF2h + tb + ln, fb[0][q], fb[1][p],
                    &bs[1][0], h2r, fb[1][q], fboff, j0, ln);
        }
        barx();
        // ---------- phase L3 ----------
        if (own) {
            layer23(WF3x + tb + ln, WF3h + tb + ln, fb[1][q], fb[2][p],
                    &bs[5][0], h3r, fb[2][q], fboff, j0, ln);
        }
        barx();
    }

    // ---------- final head (t = kT-1; fb3 parity kT&1 == 0) + final h states ----------
    if (!own) {
        head_mm(WFhd, fb[2][kT & 1], hb, out, wv - 13, kT - 1, b0, ln, lq, lr);
    } else {
        #pragma unroll
        for (int rg = 0; rg < 4; ++rg) {
            int j = j0 + rg;
            if (j < kH) {
                out[OH1 + (b0 + lr) * kH + j] = h1r[rg];
                out[OH2 + (b0 + lr) * kH + j] = h2r[rg];
                out[OH3 + (b0 + lr) * kH + j] = h3r[rg];
            }
        }
    }
}

extern "C" void kernel_launch(void* const* d_in, const int* in_sizes, int n_in,
                              void* d_out, int out_size, void* d_ws, size_t ws_size,
                              hipStream_t stream) {
    (void)in_sizes; (void)n_in; (void)out_size; (void)ws_size;
    const float* enc  = (const float*)d_in[0];
    const float* h1in = (const float*)d_in[1];
    const float* h2in = (const float*)d_in[2];
    const float* h3in = (const float*)d_in[3];
    const float* bn_g = (const float*)d_in[4];
    const float* bn_b = (const float*)d_in[5];
    const float* bn_m = (const float*)d_in[6];
    const float* bn_v = (const float*)d_in[7];
    const float* fciW = (const float*)d_in[8];
    const float* fcib = (const float*)d_in[9];
    const float* Wih1 = (const float*)d_in[10];
    const float* Whh1 = (const float*)d_in[11];
    const float* bih1 = (const float*)d_in[12];
    const float* bhh1 = (const float*)d_in[13];
    const float* Wih2 = (const float*)d_in[14];
    const float* Whh2 = (const float*)d_in[15];
    const float* bih2 = (const float*)d_in[16];
    const float* bhh2 = (const float*)d_in[17];
    const float* Wih3 = (const float*)d_in[18];
    const float* Whh3 = (const float*)d_in[19];
    const float* bih3 = (const float*)d_in[20];
    const float* bhh3 = (const float*)d_in[21];
    const float* fcoW = (const float*)d_in[22];
    const float* fcob = (const float*)d_in[23];
    float* ws  = (float*)d_ws;
    float* out = (float*)d_out;

    // order matters: prep_input consumes WIH1T/FCINT before prep_frags overwrites them
    hipLaunchKernelGGL(prep_transpose2, dim3(625), dim3(256), 0, stream, Wih1, fciW, ws);
    hipLaunchKernelGGL(prep_input, dim3(kB), dim3(256), 0, stream,
                       enc, bn_g, bn_b, bn_m, bn_v, fcib, bih1, ws);
    hipLaunchKernelGGL(prep_frags, dim3((5 * PERM2 + 4 * KS * 64 + 255) / 256), dim3(256), 0, stream,
                       Whh1, Wih2, Whh2, Wih3, Whh3, fcoW, ws);
    hipLaunchKernelGGL(gru_main, dim3(NWG), dim3(1024), 0, stream,
                       ws, h1in, h2in, h3in, bhh1, bih2, bhh2, bih3, bhh3, fcob, out);
}

// Round 7
// 1540.113 us; speedup vs baseline: 4.4074x; 1.5055x over previous
//
#include <hip/hip_runtime.h>

typedef _Float16 half8 __attribute__((ext_vector_type(8)));
typedef float f32x4 __attribute__((ext_vector_type(4)));

namespace {
constexpr int kB = 2048;
constexpr int kT = 72;
constexpr int kI = 200;
constexpr int kH = 200;
constexpr int kO = 53;
constexpr int kG = 600;      // 3*kH
constexpr int BT = 16;       // batch rows per WG
constexpr int NWG = kB / BT; // 128
constexpr int MT = 38;       // M tiles of 16 covering 608 (600 padded)
constexpr int KS = 7;        // K slices of 32 covering 224 (200 padded)
constexpr int GSTR = 18;     // LDS G col stride

// ws layout (float offsets) — identical to the proven R4 kernel
constexpr int XW1    = 0;          // [2048][600] emb@Wih1^T + bih1
constexpr int WIH1T  = 1228800;    // [200][600] Wih1^T (prep only)
constexpr int FCINT  = 1348800;    // [200][200] fc_in_W^T (prep only)
constexpr int F0     = 1388800;    // fp16 A-frags: hh1, ih2, hh2, ih3, hh3
constexpr int FSZ    = 68096;      // floats per frag matrix (38*7*64*8 halves)
constexpr int FHEAD  = F0 + 5 * FSZ;
constexpr int PERM   = MT * KS * 64;

// output offsets (floats)
constexpr int OH1 = kB * kT * kO;  // 7815168
constexpr int OH2 = OH1 + kB * kH;
constexpr int OH3 = OH2 + kB * kH;
}

__device__ __forceinline__ float sig_(float x) { return 1.0f / (1.0f + __expf(-x)); }
__device__ __forceinline__ float tanh_(float x) {
    return 1.0f - 2.0f / (__expf(2.0f * x) + 1.0f);
}

// barrier draining LDS only; in-flight global (register-dest) weight loads survive.
__device__ __forceinline__ void barx() {
    asm volatile("s_waitcnt lgkmcnt(0)\n\ts_barrier" ::: "memory");
}

// fp16 fragment-order shadow write of h element (n, j)
__device__ __forceinline__ void store_fb(_Float16* fb, int n, int j, float v) {
    int ks = j >> 5, r = j & 31;
    fb[((ks << 6) + ((r >> 3) << 4) + n) * 8 + (r & 7)] = (_Float16)v;
}

// ---------------- prep kernels (identical to R4) ----------------

__global__ __launch_bounds__(256) void prep_transpose2(
    const float* __restrict__ Wih1, const float* __restrict__ fciW,
    float* __restrict__ ws) {
    int idx = blockIdx.x * 256 + threadIdx.x;
    if (idx < 120000) {
        int k = idx / kG, c = idx - k * kG;
        ws[WIH1T + idx] = Wih1[c * kI + k];
    } else {
        int i = idx - 120000;
        if (i < 40000) {
            int k = i / kH, h = i - k * kH;
            ws[FCINT + i] = fciW[h * kI + k];
        }
    }
}

__global__ __launch_bounds__(256) void prep_frags(
    const float* __restrict__ Whh1, const float* __restrict__ Wih2,
    const float* __restrict__ Whh2, const float* __restrict__ Wih3,
    const float* __restrict__ Whh3, const float* __restrict__ fcoW,
    float* __restrict__ ws) {
    int idx = blockIdx.x * 256 + threadIdx.x;
    const float* src; int R; long long dstHalf; int rem;
    if (idx < 5 * PERM) {
        int m = idx / PERM; rem = idx - m * PERM;
        switch (m) {
            case 0: src = Whh1; break;
            case 1: src = Wih2; break;
            case 2: src = Whh2; break;
            case 3: src = Wih3; break;
            default: src = Whh3; break;
        }
        R = kG; dstHalf = 2LL * (F0 + m * FSZ);
    } else {
        rem = idx - 5 * PERM;
        if (rem >= 4 * KS * 64) return;
        src = fcoW; R = kO; dstHalf = 2LL * FHEAD;
    }
    int lane = rem & 63;
    int tmp = rem >> 6;
    int ks = tmp % KS;
    int mt = tmp / KS;
    int row = mt * 16 + (lane & 15);
    int k0 = ks * 32 + (lane >> 4) * 8;
    half8 v;
    #pragma unroll
    for (int j = 0; j < 8; ++j) {
        int k = k0 + j;
        v[j] = (_Float16)((row < R && k < kH) ? src[row * kH + k] : 0.0f);
    }
    *(half8*)((_Float16*)ws + dstHalf + (long long)rem * 8) = v;
}

__global__ __launch_bounds__(256) void prep_input(
    const float* __restrict__ enc,
    const float* __restrict__ bn_g, const float* __restrict__ bn_b,
    const float* __restrict__ bn_m, const float* __restrict__ bn_v,
    const float* __restrict__ fcib, const float* __restrict__ bih1,
    float* ws) {
    __shared__ float xh[kI];
    __shared__ float emb[kH];
    const int b = blockIdx.x, tid = threadIdx.x;
    const float* fcInT = ws + FCINT;
    const float* Wih1T = ws + WIH1T;
    if (tid < kI) {
        float x = enc[b * kI + tid];
        xh[tid] = (x - bn_m[tid]) * rsqrtf(bn_v[tid] + 1e-5f) * bn_g[tid] + bn_b[tid];
    }
    __syncthreads();
    if (tid < kH) {
        float s = fcib[tid];
        for (int k = 0; k < kI; ++k) s = fmaf(xh[k], fcInT[k * kH + tid], s);
        emb[tid] = fmaxf(s, 0.0f);
    }
    __syncthreads();
    for (int c = tid; c < kG; c += 256) {
        float s = bih1[c];
        for (int k = 0; k < kH; ++k) s = fmaf(emb[k], Wih1T[k * kG + c], s);
        ws[XW1 + b * kG + c] = s;
    }
}

// prefetch-slot load: 6 full ks-slices + predicated ks=6 pad slice
#define LDW(dst, WB, mt) do { \
    const half8* _p = (WB) + ((mt) * KS) * 64 + ln; \
    _Pragma("unroll") \
    for (int _k = 0; _k < KS - 1; ++_k) (dst)[_k] = _p[_k * 64]; \
    (dst)[KS - 1] = lo ? _p[(KS - 1) * 64] : z8; \
  } while (0)

// single-matrix tile MFMA from a register slot
__device__ __forceinline__ f32x4 mm_slot(const half8* w, const _Float16* fb, int ln) {
    f32x4 acc = {0.f, 0.f, 0.f, 0.f};
    #pragma unroll
    for (int ks = 0; ks < KS; ++ks) {
        half8 b = *(const half8*)(fb + ((ks * 64 + ln) << 3));
        acc = __builtin_amdgcn_mfma_f32_16x16x32_f16(w[ks], b, acc, 0, 0, 0);
    }
    return acc;
}

// single-matrix tile MFMA, JIT-loaded weights
__device__ __forceinline__ f32x4 mm_jit(const half8* p, const _Float16* fb,
                                        int ln, bool lo, half8 z8) {
    f32x4 acc = {0.f, 0.f, 0.f, 0.f};
    #pragma unroll
    for (int ks = 0; ks < KS; ++ks) {
        half8 w = (ks < KS - 1 || lo) ? p[ks * 64] : z8;
        half8 b = *(const half8*)(fb + ((ks * 64 + ln) << 3));
        acc = __builtin_amdgcn_mfma_f32_16x16x32_f16(w, b, acc, 0, 0, 0);
    }
    return acc;
}

// dual-matrix (x+h) tile MFMA from register slots
__device__ __forceinline__ void mm2_slot(const half8* wx, const half8* wh,
                                         const _Float16* fx, const _Float16* fh,
                                         int ln, f32x4& ax, f32x4& ah) {
    ax = {0.f, 0.f, 0.f, 0.f}; ah = {0.f, 0.f, 0.f, 0.f};
    #pragma unroll
    for (int ks = 0; ks < KS; ++ks) {
        half8 bx = *(const half8*)(fx + ((ks * 64 + ln) << 3));
        half8 bh = *(const half8*)(fh + ((ks * 64 + ln) << 3));
        ax = __builtin_amdgcn_mfma_f32_16x16x32_f16(wx[ks], bx, ax, 0, 0, 0);
        ah = __builtin_amdgcn_mfma_f32_16x16x32_f16(wh[ks], bh, ah, 0, 0, 0);
    }
}

// dual-matrix tile MFMA, JIT-loaded weights
__device__ __forceinline__ void mm2_jit(const half8* px, const half8* ph,
                                        const _Float16* fx, const _Float16* fh,
                                        int ln, bool lo, half8 z8, f32x4& ax, f32x4& ah) {
    ax = {0.f, 0.f, 0.f, 0.f}; ah = {0.f, 0.f, 0.f, 0.f};
    #pragma unroll
    for (int ks = 0; ks < KS; ++ks) {
        half8 wx = (ks < KS - 1 || lo) ? px[ks * 64] : z8;
        half8 wh = (ks < KS - 1 || lo) ? ph[ks * 64] : z8;
        half8 bx = *(const half8*)(fx + ((ks * 64 + ln) << 3));
        half8 bh = *(const half8*)(fh + ((ks * 64 + ln) << 3));
        ax = __builtin_amdgcn_mfma_f32_16x16x32_f16(wx, bx, ax, 0, 0, 0);
        ah = __builtin_amdgcn_mfma_f32_16x16x32_f16(wh, bh, ah, 0, 0, 0);
    }
}

#define GS_STORE(acc, mt) do { \
    const int _row = (mt) * 16 + lb * 4; \
    _Pragma("unroll") \
    for (int _r = 0; _r < 4; ++_r) Gs[(_row + _r) * GSTR + lr] = (acc)[_r]; \
  } while (0)

#define GS2_STORE(ax, ah, mt) do { \
    const int _row = (mt) * 16 + lb * 4; \
    if ((mt) < 25) { \
      _Pragma("unroll") \
      for (int _r = 0; _r < 4; ++_r) Gs[(_row + _r) * GSTR + lr] = (ax)[_r] + (ah)[_r]; \
    } else { \
      _Pragma("unroll") \
      for (int _r = 0; _r < 4; ++_r) { \
        Gs[(_row + _r) * GSTR + lr] = (ax)[_r]; \
        Gns[(_row - 400 + _r) * GSTR + lr] = (ah)[_r]; \
      } \
    } \
  } while (0)

// ---------------- main persistent GRU kernel ----------------
// 128 WGs x 512 threads (8 waves, 2/SIMD -> 256-VGPR budget). WG owns 16 rows.
// R4 skeleton; lgkm-only barriers; one-tile cross-phase prefetch slots; JIT
// loads inside phases. h states in registers (thread owns (n=idx&15, j=idx>>4)).
__global__ __launch_bounds__(512, 2) void gru_main(
    const float* __restrict__ ws,
    const float* __restrict__ h1in, const float* __restrict__ h2in,
    const float* __restrict__ h3in,
    const float* __restrict__ bhh1,
    const float* __restrict__ bih2, const float* __restrict__ bhh2,
    const float* __restrict__ bih3, const float* __restrict__ bhh3,
    const float* __restrict__ fcob,
    float* __restrict__ out) {
    __shared__ float xwL[kG * BT];                         // 38400 B, [j][n]
    __shared__ __align__(16) _Float16 fb1[KS * 64 * 8];
    __shared__ __align__(16) _Float16 fb2[KS * 64 * 8];
    __shared__ __align__(16) _Float16 fb3[KS * 64 * 8];
    __shared__ float Gs[608 * GSTR];
    __shared__ float Gns[208 * GSTR];
    __shared__ float bias[9 * kH];
    __shared__ float hb[64];

    const int tid = threadIdx.x, wv = tid >> 6, ln = tid & 63;
    const int lb = ln >> 4, lr = ln & 15;
    const int b0 = blockIdx.x * BT;
    const bool lo = (ln < 16);
    half8 z8;
    #pragma unroll
    for (int j = 0; j < 8; ++j) z8[j] = (_Float16)0.0f;

    // ---- stage xw1 (time-invariant) into LDS, folding bhh1 r/z biases
    for (int i = tid; i < kG * BT; i += 512) {
        int n = i / kG, j = i - n * kG;
        float v = ws[XW1 + (b0 + n) * kG + j];
        if (j < 2 * kH) v += bhh1[j];
        xwL[j * BT + n] = v;
    }
    // ---- biases: [0]=b1n [1]=b2r [2]=b2z [3]=b2xn [4]=b2hn [5..8]=L3
    for (int i = tid; i < 9 * kH; i += 512) {
        int c = i / kH, j = i - c * kH;
        float v;
        switch (c) {
            case 0:  v = bhh1[2 * kH + j]; break;
            case 1:  v = bih2[j] + bhh2[j]; break;
            case 2:  v = bih2[kH + j] + bhh2[kH + j]; break;
            case 3:  v = bih2[2 * kH + j]; break;
            case 4:  v = bhh2[2 * kH + j]; break;
            case 5:  v = bih3[j] + bhh3[j]; break;
            case 6:  v = bih3[kH + j] + bhh3[kH + j]; break;
            case 7:  v = bih3[2 * kH + j]; break;
            default: v = bhh3[2 * kH + j]; break;
        }
        bias[i] = v;
    }
    if (tid < 64) hb[tid] = (tid < kO) ? fcob[tid] : 0.0f;

    // ---- h states -> registers + fp16 frag shadows (7 guarded strides of 512)
    float h1r[7], h2r[7], h3r[7];
    #pragma unroll
    for (int s = 0; s < 7; ++s) {
        int idx = tid + s * 512;
        if (idx < BT * kH) {
            int n = idx & 15, j = idx >> 4;
            h1r[s] = h1in[(b0 + n) * kH + j];
            h2r[s] = h2in[(b0 + n) * kH + j];
            h3r[s] = h3in[(b0 + n) * kH + j];
            store_fb(fb1, n, j, h1r[s]);
            store_fb(fb2, n, j, h2r[s]);
            store_fb(fb3, n, j, h3r[s]);
        } else { h1r[s] = h2r[s] = h3r[s] = 0.0f; }
    }
    // zero fp16 K-pad (ks=6, k=200..223 -> frag lanes 16..63)
    for (int i = tid; i < 3 * 48 * 8; i += 512) {
        int w = i / 384, r = i - w * 384;
        int lane = 16 + (r >> 3), jj = r & 7;
        _Float16* f = (w == 0) ? fb1 : (w == 1) ? fb2 : fb3;
        f[(6 * 64 + lane) * 8 + jj] = (_Float16)0.0f;
    }
    __syncthreads();

    const half8* WFhh1 = (const half8*)(ws + F0);
    const half8* WFih2 = (const half8*)(ws + F0 + FSZ);
    const half8* WFhh2 = (const half8*)(ws + F0 + 2 * FSZ);
    const half8* WFih3 = (const half8*)(ws + F0 + 3 * FSZ);
    const half8* WFhh3 = (const half8*)(ws + F0 + 4 * FSZ);
    const half8* WFhead = (const half8*)(ws + FHEAD);

    // ---- prefetch slots (one 16-row tile each): 28 VGPR per slot
    half8 p1[KS], p2x[KS], p2h[KS], p3x[KS], p3h[KS], whd[KS];

    LDW(p1, WFhh1, wv);
    if (wv < 4) {
        const half8* _p = WFhead + (wv * KS) * 64 + ln;
        #pragma unroll
        for (int k = 0; k < KS; ++k) whd[k] = _p[k * 64];
    }

    for (int t = 0; t < kT; ++t) {
        // ---------- M1: Gs = Whh1 x h1 (slot tile, then JIT tiles); prefetch ih2/hh2 ----------
        {
            f32x4 acc = mm_slot(p1, fb1, ln);
            GS_STORE(acc, wv);
            for (int mt = wv + 8; mt < MT; mt += 8) {
                f32x4 a = mm_jit(WFhh1 + (mt * KS) * 64 + ln, fb1, ln, lo, z8);
                GS_STORE(a, mt);
            }
            LDW(p2x, WFih2, wv);
            LDW(p2h, WFhh2, wv);
        }
        barx();
        // ---------- U1: update h1 ----------
        #pragma unroll
        for (int s = 0; s < 7; ++s) {
            int idx = tid + s * 512;
            if (idx < BT * kH) {
                int n = idx & 15, j = idx >> 4;
                float r  = sig_(xwL[j * BT + n]            + Gs[j * GSTR + n]);
                float z  = sig_(xwL[(kH + j) * BT + n]     + Gs[(kH + j) * GSTR + n]);
                float nn = tanh_(xwL[(2 * kH + j) * BT + n] + r * (Gs[(2 * kH + j) * GSTR + n] + bias[j]));
                h1r[s] = (1.0f - z) * nn + z * h1r[s];
                store_fb(fb1, n, j, h1r[s]);
            }
        }
        barx();
        // ---------- M2: Wih2 x h1 + Whh2 x h2; prefetch ih3/hh3 ----------
        {
            f32x4 ax, ah;
            mm2_slot(p2x, p2h, fb1, fb2, ln, ax, ah);
            GS2_STORE(ax, ah, wv);
            for (int mt = wv + 8; mt < MT; mt += 8) {
                mm2_jit(WFih2 + (mt * KS) * 64 + ln, WFhh2 + (mt * KS) * 64 + ln,
                        fb1, fb2, ln, lo, z8, ax, ah);
                GS2_STORE(ax, ah, mt);
            }
            LDW(p3x, WFih3, wv);
            LDW(p3h, WFhh3, wv);
        }
        barx();
        // ---------- U2: update h2 ----------
        #pragma unroll
        for (int s = 0; s < 7; ++s) {
            int idx = tid + s * 512;
            if (idx < BT * kH) {
                int n = idx & 15, j = idx >> 4;
                float r  = sig_(Gs[j * GSTR + n]            + bias[kH + j]);
                float z  = sig_(Gs[(kH + j) * GSTR + n]     + bias[2 * kH + j]);
                float nn = tanh_(Gs[(2 * kH + j) * GSTR + n] + bias[3 * kH + j]
                                 + r * (Gns[j * GSTR + n]   + bias[4 * kH + j]));
                h2r[s] = (1.0f - z) * nn + z * h2r[s];
                store_fb(fb2, n, j, h2r[s]);
            }
        }
        barx();
        // ---------- M3: Wih3 x h2 + Whh3 x h3; prefetch next-step hh1 ----------
        {
            f32x4 ax, ah;
            mm2_slot(p3x, p3h, fb2, fb3, ln, ax, ah);
            GS2_STORE(ax, ah, wv);
            for (int mt = wv + 8; mt < MT; mt += 8) {
                mm2_jit(WFih3 + (mt * KS) * 64 + ln, WFhh3 + (mt * KS) * 64 + ln,
                        fb2, fb3, ln, lo, z8, ax, ah);
                GS2_STORE(ax, ah, mt);
            }
            LDW(p1, WFhh1, wv);
        }
        barx();
        // ---------- U3: update h3 ----------
        #pragma unroll
        for (int s = 0; s < 7; ++s) {
            int idx = tid + s * 512;
            if (idx < BT * kH) {
                int n = idx & 15, j = idx >> 4;
                float r  = sig_(Gs[j * GSTR + n]            + bias[5 * kH + j]);
                float z  = sig_(Gs[(kH + j) * GSTR + n]     + bias[6 * kH + j]);
                float nn = tanh_(Gs[(2 * kH + j) * GSTR + n] + bias[7 * kH + j]
                                 + r * (Gns[j * GSTR + n]   + bias[8 * kH + j]));
                h3r[s] = (1.0f - z) * nn + z * h3r[s];
                store_fb(fb3, n, j, h3r[s]);
            }
        }
        barx();
        // ---------- HEAD (waves 0..3): sigmoid(h3 @ fc_out^T + b) ----------
        if (wv < 4) {
            f32x4 acc = mm_slot(whd, fb3, ln);
            int o0 = wv * 16 + lb * 4;
            int obase = (b0 + lr) * (kT * kO) + t * kO;
            #pragma unroll
            for (int rg = 0; rg < 4; ++rg) {
                int o = o0 + rg;
                if (o < kO) out[obase + o] = sig_(acc[rg] + hb[o]);
            }
        }
        barx();
    }

    // ---- final hidden states: stage in LDS (Gs) for coalesced global writes
    #pragma unroll
    for (int s = 0; s < 7; ++s) {
        int idx = tid + s * 512;
        if (idx < BT * kH) {
            Gs[idx] = h1r[s];
            Gs[3200 + idx] = h2r[s];
            Gs[6400 + idx] = h3r[s];
        }
    }
    __syncthreads();
    for (int i = tid; i < BT * kH; i += 512) {
        int n = i / kH, j = i - n * kH;
        int src = j * BT + n;
        out[OH1 + (b0 + n) * kH + j] = Gs[src];
        out[OH2 + (b0 + n) * kH + j] = Gs[3200 + src];
        out[OH3 + (b0 + n) * kH + j] = Gs[6400 + src];
    }
}

extern "C" void kernel_launch(void* const* d_in, const int* in_sizes, int n_in,
                              void* d_out, int out_size, void* d_ws, size_t ws_size,
                              hipStream_t stream) {
    (void)in_sizes; (void)n_in; (void)out_size; (void)ws_size;
    const float* enc  = (const float*)d_in[0];
    const float* h1in = (const float*)d_in[1];
    const float* h2in = (const float*)d_in[2];
    const float* h3in = (const float*)d_in[3];
    const float* bn_g = (const float*)d_in[4];
    const float* bn_b = (const float*)d_in[5];
    const float* bn_m = (const float*)d_in[6];
    const float* bn_v = (const float*)d_in[7];
    const float* fciW = (const float*)d_in[8];
    const float* fcib = (const float*)d_in[9];
    const float* Wih1 = (const float*)d_in[10];
    const float* Whh1 = (const float*)d_in[11];
    const float* bih1 = (const float*)d_in[12];
    const float* bhh1 = (const float*)d_in[13];
    const float* Wih2 = (const float*)d_in[14];
    const float* Whh2 = (const float*)d_in[15];
    const float* bih2 = (const float*)d_in[16];
    const float* bhh2 = (const float*)d_in[17];
    const float* Wih3 = (const float*)d_in[18];
    const float* Whh3 = (const float*)d_in[19];
    const float* bih3 = (const float*)d_in[20];
    const float* bhh3 = (const float*)d_in[21];
    const float* fcoW = (const float*)d_in[22];
    const float* fcob = (const float*)d_in[23];
    float* ws  = (float*)d_ws;
    float* out = (float*)d_out;

    hipLaunchKernelGGL(prep_transpose2, dim3(625), dim3(256), 0, stream, Wih1, fciW, ws);
    hipLaunchKernelGGL(prep_frags, dim3(340), dim3(256), 0, stream,
                       Whh1, Wih2, Whh2, Wih3, Whh3, fcoW, ws);
    hipLaunchKernelGGL(prep_input, dim3(kB), dim3(256), 0, stream,
                       enc, bn_g, bn_b, bn_m, bn_v, fcib, bih1, ws);
    hipLaunchKernelGGL(gru_main, dim3(NWG), dim3(512), 0, stream,
                       ws, h1in, h2in, h3in, bhh1, bih2, bhh2, bih3, bhh3, fcob, out);
}

// Round 9
// 1150.668 us; speedup vs baseline: 5.8991x; 1.3385x over previous
//
#include <hip/hip_runtime.h>

typedef _Float16 half8 __attribute__((ext_vector_type(8)));
typedef float f32x4 __attribute__((ext_vector_type(4)));

namespace {
constexpr int kB = 2048;
constexpr int kT = 72;
constexpr int kI = 200;
constexpr int kH = 200;
constexpr int kO = 53;
constexpr int kG = 600;      // 3*kH
constexpr int BT = 8;        // batch rows per WG (8 -> 256 WGs -> all 256 CUs)
constexpr int NWG = kB / BT; // 256
constexpr int MT = 38;       // M tiles of 16 covering 608 (600 padded)
constexpr int KS = 7;        // K slices of 32 covering 224 (200 padded)
constexpr int GSTR = 18;     // LDS G col stride

// ws layout (float offsets) — identical to R4
constexpr int XW1    = 0;          // [2048][600] emb@Wih1^T + bih1
constexpr int WIH1T  = 1228800;    // [200][600] Wih1^T (prep only)
constexpr int FCINT  = 1348800;    // [200][200] fc_in_W^T (prep only)
constexpr int F0     = 1388800;    // fp16 A-frags: hh1, ih2, hh2, ih3, hh3
constexpr int FSZ    = 68096;      // floats per frag matrix
constexpr int FHEAD  = F0 + 5 * FSZ;
constexpr int PERM   = MT * KS * 64;

// output offsets (floats)
constexpr int OH1 = kB * kT * kO;  // 7815168
constexpr int OH2 = OH1 + kB * kH;
constexpr int OH3 = OH2 + kB * kH;
}

__device__ __forceinline__ float sig_(float x) { return 1.0f / (1.0f + __expf(-x)); }
__device__ __forceinline__ float tanh_(float x) {
    return 1.0f - 2.0f / (__expf(2.0f * x) + 1.0f);
}

// barrier draining LDS only; in-flight global weight loads survive (validated R6/R7).
__device__ __forceinline__ void barx() {
    asm volatile("s_waitcnt lgkmcnt(0)\n\ts_barrier" ::: "memory");
}

// fp16 fragment-order shadow write of h element (n, j); n < BT
__device__ __forceinline__ void store_fb(_Float16* fb, int n, int j, float v) {
    int ks = j >> 5, r = j & 31;
    fb[((ks << 6) + ((r >> 3) << 4) + n) * 8 + (r & 7)] = (_Float16)v;
}

// ---------------- prep kernels (identical to R4) ----------------

__global__ __launch_bounds__(256) void prep_transpose2(
    const float* __restrict__ Wih1, const float* __restrict__ fciW,
    float* __restrict__ ws) {
    int idx = blockIdx.x * 256 + threadIdx.x;
    if (idx < 120000) {
        int k = idx / kG, c = idx - k * kG;
        ws[WIH1T + idx] = Wih1[c * kI + k];
    } else {
        int i = idx - 120000;
        if (i < 40000) {
            int k = i / kH, h = i - k * kH;
            ws[FCINT + i] = fciW[h * kI + k];
        }
    }
}

__global__ __launch_bounds__(256) void prep_frags(
    const float* __restrict__ Whh1, const float* __restrict__ Wih2,
    const float* __restrict__ Whh2, const float* __restrict__ Wih3,
    const float* __restrict__ Whh3, const float* __restrict__ fcoW,
    float* __restrict__ ws) {
    int idx = blockIdx.x * 256 + threadIdx.x;
    const float* src; int R; long long dstHalf; int rem;
    if (idx < 5 * PERM) {
        int m = idx / PERM; rem = idx - m * PERM;
        switch (m) {
            case 0: src = Whh1; break;
            case 1: src = Wih2; break;
            case 2: src = Whh2; break;
            case 3: src = Wih3; break;
            default: src = Whh3; break;
        }
        R = kG; dstHalf = 2LL * (F0 + m * FSZ);
    } else {
        rem = idx - 5 * PERM;
        if (rem >= 4 * KS * 64) return;
        src = fcoW; R = kO; dstHalf = 2LL * FHEAD;
    }
    int lane = rem & 63;
    int tmp = rem >> 6;
    int ks = tmp % KS;
    int mt = tmp / KS;
    int row = mt * 16 + (lane & 15);
    int k0 = ks * 32 + (lane >> 4) * 8;
    half8 v;
    #pragma unroll
    for (int j = 0; j < 8; ++j) {
        int k = k0 + j;
        v[j] = (_Float16)((row < R && k < kH) ? src[row * kH + k] : 0.0f);
    }
    *(half8*)((_Float16*)ws + dstHalf + (long long)rem * 8) = v;
}

__global__ __launch_bounds__(256) void prep_input(
    const float* __restrict__ enc,
    const float* __restrict__ bn_g, const float* __restrict__ bn_b,
    const float* __restrict__ bn_m, const float* __restrict__ bn_v,
    const float* __restrict__ fcib, const float* __restrict__ bih1,
    float* ws) {
    __shared__ float xh[kI];
    __shared__ float emb[kH];
    const int b = blockIdx.x, tid = threadIdx.x;
    const float* fcInT = ws + FCINT;
    const float* Wih1T = ws + WIH1T;
    if (tid < kI) {
        float x = enc[b * kI + tid];
        xh[tid] = (x - bn_m[tid]) * rsqrtf(bn_v[tid] + 1e-5f) * bn_g[tid] + bn_b[tid];
    }
    __syncthreads();
    if (tid < kH) {
        float s = fcib[tid];
        for (int k = 0; k < kI; ++k) s = fmaf(xh[k], fcInT[k * kH + tid], s);
        emb[tid] = fmaxf(s, 0.0f);
    }
    __syncthreads();
    for (int c = tid; c < kG; c += 256) {
        float s = bih1[c];
        for (int k = 0; k < kH; ++k) s = fmaf(emb[k], Wih1T[k * kG + c], s);
        ws[XW1 + b * kG + c] = s;
    }
}

// ---------------- main persistent GRU kernel ----------------
// 256 WGs x 1024 threads (16 waves), one per CU. WG owns 8 batch rows.
// R4 skeleton; lgkm-only barriers. fb B-columns 8..15 are zeroed at init and
// never written after, so all MFMA garbage columns are exact zeros. All MFMA
// executes wave-uniform; only stores are lane-guarded.
__global__ __launch_bounds__(1024, 4) void gru_main(
    const float* __restrict__ ws,
    const float* __restrict__ h1in, const float* __restrict__ h2in,
    const float* __restrict__ h3in,
    const float* __restrict__ bhh1,
    const float* __restrict__ bih2, const float* __restrict__ bhh2,
    const float* __restrict__ bih3, const float* __restrict__ bhh3,
    const float* __restrict__ fcob,
    float* __restrict__ out) {
    __shared__ float xwL[kG * BT];                         // 19200 B, [j][n]
    __shared__ __align__(16) _Float16 fb1[KS * 64 * 8];    // 7168 B each
    __shared__ __align__(16) _Float16 fb2[KS * 64 * 8];
    __shared__ __align__(16) _Float16 fb3[KS * 64 * 8];
    __shared__ float Gs[608 * GSTR];                       // 43776 B
    __shared__ float Gns[208 * GSTR];                      // 14976 B
    __shared__ float bias[9 * kH];                         // 7200 B
    __shared__ float hb[64];

    const int tid = threadIdx.x, wv = tid >> 6, ln = tid & 63;
    const int lb = ln >> 4, lr = ln & 15;
    const int b0 = blockIdx.x * BT;

    // ---- zero ALL fb slots first (garbage batch-columns 8..15 + K-pad become 0)
    {
        float4* f1 = (float4*)fb1;
        float4* f2 = (float4*)fb2;
        float4* f3 = (float4*)fb3;
        const float4 z4 = {0.f, 0.f, 0.f, 0.f};
        for (int i = tid; i < KS * 64 * 8 * 2 / 16; i += 1024) {  // 448 float4 each
            f1[i] = z4; f2[i] = z4; f3[i] = z4;
        }
    }
    // ---- stage xw1 (time-invariant) into LDS, folding bhh1 r/z biases
    for (int i = tid; i < kG * BT; i += 1024) {
        int n = i / kG, j = i - n * kG;
        float v = ws[XW1 + (b0 + n) * kG + j];
        if (j < 2 * kH) v += bhh1[j];
        xwL[j * BT + n] = v;
    }
    // ---- biases: [0]=b1n [1]=b2r [2]=b2z [3]=b2xn [4]=b2hn [5..8]=L3
    for (int i = tid; i < 9 * kH; i += 1024) {
        int c = i / kH, j = i - c * kH;
        float v;
        switch (c) {
            case 0:  v = bhh1[2 * kH + j]; break;
            case 1:  v = bih2[j] + bhh2[j]; break;
            case 2:  v = bih2[kH + j] + bhh2[kH + j]; break;
            case 3:  v = bih2[2 * kH + j]; break;
            case 4:  v = bhh2[2 * kH + j]; break;
            case 5:  v = bih3[j] + bhh3[j]; break;
            case 6:  v = bih3[kH + j] + bhh3[kH + j]; break;
            case 7:  v = bih3[2 * kH + j]; break;
            default: v = bhh3[2 * kH + j]; break;
        }
        bias[i] = v;
    }
    if (tid < 64) hb[tid] = (tid < kO) ? fcob[tid] : 0.0f;
    __syncthreads();   // fb zeroing complete before shadow writes

    // ---- h states -> registers + fp16 frag shadows (BT*kH = 1600 elems)
    float h1r[2], h2r[2], h3r[2];
    #pragma unroll
    for (int s = 0; s < 2; ++s) {
        int idx = tid + s * 1024;
        if (idx < BT * kH) {
            int n = idx & 7, j = idx >> 3;
            h1r[s] = h1in[(b0 + n) * kH + j];
            h2r[s] = h2in[(b0 + n) * kH + j];
            h3r[s] = h3in[(b0 + n) * kH + j];
            store_fb(fb1, n, j, h1r[s]);
            store_fb(fb2, n, j, h2r[s]);
            store_fb(fb3, n, j, h3r[s]);
        } else { h1r[s] = h2r[s] = h3r[s] = 0.0f; }
    }
    __syncthreads();

    const half8* WFhh1 = (const half8*)(ws + F0);
    const half8* WFih2 = (const half8*)(ws + F0 + FSZ);
    const half8* WFhh2 = (const half8*)(ws + F0 + 2 * FSZ);
    const half8* WFih3 = (const half8*)(ws + F0 + 3 * FSZ);
    const half8* WFhh3 = (const half8*)(ws + F0 + 4 * FSZ);
    const half8* WFhead = (const half8*)(ws + FHEAD);

    for (int t = 0; t < kT; ++t) {
        // ---------- M1: Gs = Whh1 x h1 ----------
        {
            half8 bf[KS];
            #pragma unroll
            for (int ks = 0; ks < KS; ++ks)
                bf[ks] = *(const half8*)(fb1 + (ks * 64 + ln) * 8);
            for (int mt = wv; mt < MT; mt += 16) {
                const half8* wp = WFhh1 + (mt * KS) * 64 + ln;
                f32x4 acc = {0.f, 0.f, 0.f, 0.f};
                #pragma unroll
                for (int ks = 0; ks < KS; ++ks)
                    acc = __builtin_amdgcn_mfma_f32_16x16x32_f16(wp[ks * 64], bf[ks], acc, 0, 0, 0);
                int row = mt * 16 + lb * 4;
                #pragma unroll
                for (int rg = 0; rg < 4; ++rg) Gs[(row + rg) * GSTR + lr] = acc[rg];
            }
        }
        barx();
        // ---------- U1: update h1 ----------
        #pragma unroll
        for (int s = 0; s < 2; ++s) {
            int idx = tid + s * 1024;
            if (idx < BT * kH) {
                int n = idx & 7, j = idx >> 3;
                float r  = sig_(xwL[j * BT + n]            + Gs[j * GSTR + n]);
                float z  = sig_(xwL[(kH + j) * BT + n]     + Gs[(kH + j) * GSTR + n]);
                float nn = tanh_(xwL[(2 * kH + j) * BT + n] + r * (Gs[(2 * kH + j) * GSTR + n] + bias[j]));
                h1r[s] = (1.0f - z) * nn + z * h1r[s];
                store_fb(fb1, n, j, h1r[s]);
            }
        }
        barx();
        // ---------- M2: Wih2 x h1 + Whh2 x h2 ----------
        {
            half8 bx[KS], bh[KS];
            #pragma unroll
            for (int ks = 0; ks < KS; ++ks) {
                bx[ks] = *(const half8*)(fb1 + (ks * 64 + ln) * 8);
                bh[ks] = *(const half8*)(fb2 + (ks * 64 + ln) * 8);
            }
            for (int mt = wv; mt < MT; mt += 16) {
                const half8* wpx = WFih2 + (mt * KS) * 64 + ln;
                const half8* wph = WFhh2 + (mt * KS) * 64 + ln;
                f32x4 ax = {0.f, 0.f, 0.f, 0.f}, ah = {0.f, 0.f, 0.f, 0.f};
                #pragma unroll
                for (int ks = 0; ks < KS; ++ks) {
                    ax = __builtin_amdgcn_mfma_f32_16x16x32_f16(wpx[ks * 64], bx[ks], ax, 0, 0, 0);
                    ah = __builtin_amdgcn_mfma_f32_16x16x32_f16(wph[ks * 64], bh[ks], ah, 0, 0, 0);
                }
                int row = mt * 16 + lb * 4;
                if (mt < 25) {
                    #pragma unroll
                    for (int rg = 0; rg < 4; ++rg) Gs[(row + rg) * GSTR + lr] = ax[rg] + ah[rg];
                } else {
                    #pragma unroll
                    for (int rg = 0; rg < 4; ++rg) {
                        Gs[(row + rg) * GSTR + lr] = ax[rg];
                        Gns[(row - 400 + rg) * GSTR + lr] = ah[rg];
                    }
                }
            }
        }
        barx();
        // ---------- U2: update h2 ----------
        #pragma unroll
        for (int s = 0; s < 2; ++s) {
            int idx = tid + s * 1024;
            if (idx < BT * kH) {
                int n = idx & 7, j = idx >> 3;
                float r  = sig_(Gs[j * GSTR + n]            + bias[kH + j]);
                float z  = sig_(Gs[(kH + j) * GSTR + n]     + bias[2 * kH + j]);
                float nn = tanh_(Gs[(2 * kH + j) * GSTR + n] + bias[3 * kH + j]
                                 + r * (Gns[j * GSTR + n]   + bias[4 * kH + j]));
                h2r[s] = (1.0f - z) * nn + z * h2r[s];
                store_fb(fb2, n, j, h2r[s]);
            }
        }
        barx();
        // ---------- M3: Wih3 x h2 + Whh3 x h3 ----------
        {
            half8 bx[KS], bh[KS];
            #pragma unroll
            for (int ks = 0; ks < KS; ++ks) {
                bx[ks] = *(const half8*)(fb2 + (ks * 64 + ln) * 8);
                bh[ks] = *(const half8*)(fb3 + (ks * 64 + ln) * 8);
            }
            for (int mt = wv; mt < MT; mt += 16) {
                const half8* wpx = WFih3 + (mt * KS) * 64 + ln;
                const half8* wph = WFhh3 + (mt * KS) * 64 + ln;
                f32x4 ax = {0.f, 0.f, 0.f, 0.f}, ah = {0.f, 0.f, 0.f, 0.f};
                #pragma unroll
                for (int ks = 0; ks < KS; ++ks) {
                    ax = __builtin_amdgcn_mfma_f32_16x16x32_f16(wpx[ks * 64], bx[ks], ax, 0, 0, 0);
                    ah = __builtin_amdgcn_mfma_f32_16x16x32_f16(wph[ks * 64], bh[ks], ah, 0, 0, 0);
                }
                int row = mt * 16 + lb * 4;
                if (mt < 25) {
                    #pragma unroll
                    for (int rg = 0; rg < 4; ++rg) Gs[(row + rg) * GSTR + lr] = ax[rg] + ah[rg];
                } else {
                    #pragma unroll
                    for (int rg = 0; rg < 4; ++rg) {
                        Gs[(row + rg) * GSTR + lr] = ax[rg];
                        Gns[(row - 400 + rg) * GSTR + lr] = ah[rg];
                    }
                }
            }
        }
        barx();
        // ---------- U3: update h3 ----------
        #pragma unroll
        for (int s = 0; s < 2; ++s) {
            int idx = tid + s * 1024;
            if (idx < BT * kH) {
                int n = idx & 7, j = idx >> 3;
                float r  = sig_(Gs[j * GSTR + n]            + bias[5 * kH + j]);
                float z  = sig_(Gs[(kH + j) * GSTR + n]     + bias[6 * kH + j]);
                float nn = tanh_(Gs[(2 * kH + j) * GSTR + n] + bias[7 * kH + j]
                                 + r * (Gns[j * GSTR + n]   + bias[8 * kH + j]));
                h3r[s] = (1.0f - z) * nn + z * h3r[s];
                store_fb(fb3, n, j, h3r[s]);
            }
        }
        barx();
        // ---------- HEAD (waves 0..3, wave-uniform MFMA; stores guarded) ----------
        if (wv < 4) {
            half8 bf[KS];
            #pragma unroll
            for (int ks = 0; ks < KS; ++ks)
                bf[ks] = *(const half8*)(fb3 + (ks * 64 + ln) * 8);
            const half8* wp = WFhead + (wv * KS) * 64 + ln;
            f32x4 acc = {0.f, 0.f, 0.f, 0.f};
            #pragma unroll
            for (int ks = 0; ks < KS; ++ks)
                acc = __builtin_amdgcn_mfma_f32_16x16x32_f16(wp[ks * 64], bf[ks], acc, 0, 0, 0);
            if (lr < BT) {
                int o0 = wv * 16 + lb * 4;
                int obase = (b0 + lr) * (kT * kO) + t * kO;
                #pragma unroll
                for (int rg = 0; rg < 4; ++rg) {
                    int o = o0 + rg;
                    if (o < kO) out[obase + o] = sig_(acc[rg] + hb[o]);
                }
            }
        }
        barx();
    }

    // ---- final hidden states: stage in LDS (Gs) for coalesced global writes
    #pragma unroll
    for (int s = 0; s < 2; ++s) {
        int idx = tid + s * 1024;
        if (idx < BT * kH) {
            Gs[idx] = h1r[s];
            Gs[1600 + idx] = h2r[s];
            Gs[3200 + idx] = h3r[s];
        }
    }
    __syncthreads();
    for (int i = tid; i < BT * kH; i += 1024) {
        int n = i / kH, j = i - n * kH;
        int src = j * BT + n;
        out[OH1 + (b0 + n) * kH + j] = Gs[src];
        out[OH2 + (b0 + n) * kH + j] = Gs[1600 + src];
        out[OH3 + (b0 + n) * kH + j] = Gs[3200 + src];
    }
}

extern "C" void kernel_launch(void* const* d_in, const int* in_sizes, int n_in,
                              void* d_out, int out_size, void* d_ws, size_t ws_size,
                              hipStream_t stream) {
    (void)in_sizes; (void)n_in; (void)out_size; (void)ws_size;
    const float* enc  = (const float*)d_in[0];
    const float* h1in = (const float*)d_in[1];
    const float* h2in = (const float*)d_in[2];
    const float* h3in = (const float*)d_in[3];
    const float* bn_g = (const float*)d_in[4];
    const float* bn_b = (const float*)d_in[5];
    const float* bn_m = (const float*)d_in[6];
    const float* bn_v = (const float*)d_in[7];
    const float* fciW = (const float*)d_in[8];
    const float* fcib = (const float*)d_in[9];
    const float* Wih1 = (const float*)d_in[10];
    const float* Whh1 = (const float*)d_in[11];
    const float* bih1 = (const float*)d_in[12];
    const float* bhh1 = (const float*)d_in[13];
    const float* Wih2 = (const float*)d_in[14];
    const float* Whh2 = (const float*)d_in[15];
    const float* bih2 = (const float*)d_in[16];
    const float* bhh2 = (const float*)d_in[17];
    const float* Wih3 = (const float*)d_in[18];
    const float* Whh3 = (const float*)d_in[19];
    const float* bih3 = (const float*)d_in[20];
    const float* bhh3 = (const float*)d_in[21];
    const float* fcoW = (const float*)d_in[22];
    const float* fcob = (const float*)d_in[23];
    float* ws  = (float*)d_ws;
    float* out = (float*)d_out;

    hipLaunchKernelGGL(prep_transpose2, dim3(625), dim3(256), 0, stream, Wih1, fciW, ws);
    hipLaunchKernelGGL(prep_frags, dim3(340), dim3(256), 0, stream,
                       Whh1, Wih2, Whh2, Wih3, Whh3, fcoW, ws);
    hipLaunchKernelGGL(prep_input, dim3(kB), dim3(256), 0, stream,
                       enc, bn_g, bn_b, bn_m, bn_v, fcib, bih1, ws);
    hipLaunchKernelGGL(gru_main, dim3(NWG), dim3(1024), 0, stream,
                       ws, h1in, h2in, h3in, bhh1, bih2, bhh2, bih3, bhh3, fcob, out);
}